// Round 3
// baseline (1978.889 us; speedup 1.0000x reference)
//
#include <hip/hip_runtime.h>

#define N_NODES 100000
#define N_EDGES 1600000
#define NEG_SLOPE 0.01f
#define NPAD 102400
#define NPB 128              // nodes per bucket (dst >> 7)
#define NBUCK 782            // ceil(100000/128)
#define CAP 2304             // bucket capacity: mean 2046, +5.7 sigma

// ---------------------------------------------------------------------------
// zero bucket counters
// ---------------------------------------------------------------------------
__global__ void k_zero(int* __restrict__ bcnt) {
    bcnt[blockIdx.x * 256 + threadIdx.x] = 0;
}

// ---------------------------------------------------------------------------
// Bucket scatter: record = (dst&127)<<24 | src  ->  ebuf[bucket*CAP + pos]
// ---------------------------------------------------------------------------
__global__ void k_bucket(const int* __restrict__ src, const int* __restrict__ dst,
                         int* __restrict__ bcnt, unsigned int* __restrict__ ebuf) {
    int idx = blockIdx.x * blockDim.x + threadIdx.x;
    int stride = gridDim.x * blockDim.x;
    for (int e = idx; e < N_EDGES; e += stride) {
        int d = dst[e];
        int b = d >> 7;
        int pos = atomicAdd(&bcnt[b], 1);
        if (pos < CAP)
            ebuf[(size_t)b * CAP + pos] =
                (unsigned int)src[e] | ((unsigned int)(d & 127) << 24);
    }
}

// ---------------------------------------------------------------------------
// Per-bucket in-degree histogram -> dinv = rsqrt(deg+1)
// ---------------------------------------------------------------------------
__global__ __launch_bounds__(256) void k_degb(const unsigned int* __restrict__ ebuf,
                                              const int* __restrict__ bcnt,
                                              float* __restrict__ dinv) {
    __shared__ int cnt[NPB];
    const int b = blockIdx.x, tid = threadIdx.x;
    if (tid < NPB) cnt[tid] = 0;
    __syncthreads();
    int n = bcnt[b]; if (n > CAP) n = CAP;
    const unsigned int* eb = ebuf + (size_t)b * CAP;
    for (int i = tid; i < n; i += 256) atomicAdd(&cnt[eb[i] >> 24], 1);
    __syncthreads();
    if (tid < NPB) {
        int node = b * NPB + tid;
        if (node < N_NODES) dinv[node] = rsqrtf((float)(cnt[tid] + 1));
    }
}

// ---------------------------------------------------------------------------
// Y[N,64] = (LEAKY? leaky(X) : X)[N,K] @ W[K,64]   (unchanged)
// ---------------------------------------------------------------------------
template <int K, bool LEAKY>
__global__ __launch_bounds__(256) void k_gemm(const float* __restrict__ X,
                                              const float* __restrict__ W,
                                              float* __restrict__ Y) {
    __shared__ float ws[K * 64];
    __shared__ __align__(16) float xs[16][K];
    const int tid = threadIdx.x;
    for (int i = tid; i < K * 64; i += 256) ws[i] = W[i];
    const int row0 = blockIdx.x * 16;
    for (int i = tid; i < 16 * K; i += 256) {
        int r = i / K, k = i % K;
        float v = X[(row0 + r) * K + k];
        if (LEAKY) v = (v >= 0.f) ? v : NEG_SLOPE * v;
        xs[r][k] = v;
    }
    __syncthreads();
    const int c = tid & 63, rq = tid >> 6;
    float acc[4] = {0.f, 0.f, 0.f, 0.f};
    const float4* xs4 = reinterpret_cast<const float4*>(&xs[0][0]);
    for (int k = 0; k < K; k += 4) {
        float w0 = ws[(k + 0) * 64 + c];
        float w1 = ws[(k + 1) * 64 + c];
        float w2 = ws[(k + 2) * 64 + c];
        float w3 = ws[(k + 3) * 64 + c];
        const int kq = k >> 2;
#pragma unroll
        for (int j = 0; j < 4; ++j) {
            float4 xv = xs4[(rq * 4 + j) * (K / 4) + kq];
            acc[j] = fmaf(xv.x, w0, acc[j]);
            acc[j] = fmaf(xv.y, w1, acc[j]);
            acc[j] = fmaf(xv.z, w2, acc[j]);
            acc[j] = fmaf(xv.w, w3, acc[j]);
        }
    }
#pragma unroll
    for (int j = 0; j < 4; ++j)
        Y[(row0 + rq * 4 + j) * 64 + c] = acc[j];
}

// ---------------------------------------------------------------------------
// Bucketed aggregation with LDS accumulator. One block per bucket.
// accum[dl,lane] += h[src,lane] * dinv[src]*dinv[dst]; then
// out = accum + h[node]*dinv^2 + bias
// ---------------------------------------------------------------------------
__global__ __launch_bounds__(256) void k_aggb(const unsigned int* __restrict__ ebuf,
                                              const int* __restrict__ bcnt,
                                              const float* __restrict__ dinv,
                                              const float* __restrict__ h,
                                              const float* __restrict__ bias,
                                              float* __restrict__ out) {
    __shared__ float accum[NPB * 64];   // 32 KiB
    __shared__ float dloc[NPB];
    const int b = blockIdx.x;
    const int tid = threadIdx.x;
    const int lane = tid & 63, wv = tid >> 6;
    const int base = b * NPB;
    for (int i = tid; i < NPB * 64; i += 256) accum[i] = 0.f;
    if (tid < NPB) {
        int node = base + tid;
        dloc[tid] = (node < N_NODES) ? dinv[node] : 0.f;
    }
    __syncthreads();
    int cnt = bcnt[b]; if (cnt > CAP) cnt = CAP;
    const unsigned int* eb = ebuf + (size_t)b * CAP;
    for (int c0 = wv * 64; c0 < cnt; c0 += 256) {
        int nv = min(64, cnt - c0);
        unsigned int p = 0;
        float wl = 0.f;
        if (lane < nv) {
            p = eb[c0 + lane];
            int s = p & 0xFFFFFF;
            wl = dinv[s] * dloc[p >> 24];
        }
        for (int j = 0; j < nv; ++j) {
            unsigned int pj = __shfl(p, j);
            float wj = __shfl(wl, j);
            int s = pj & 0xFFFFFF;
            int dl = pj >> 24;
            float hv = h[(size_t)s * 64 + lane];
            atomicAdd(&accum[dl * 64 + lane], hv * wj);
        }
    }
    __syncthreads();
    for (int r = wv; r < NPB; r += 4) {
        int node = base + r;
        if (node >= N_NODES) continue;
        float dv = dloc[r];
        out[(size_t)node * 64 + lane] =
            accum[r * 64 + lane] + h[(size_t)node * 64 + lane] * (dv * dv) + bias[lane];
    }
}

// ---------------------------------------------------------------------------
// out[N,4] = H[N,64] @ Wfc[64,4] + bfc   (unchanged)
// ---------------------------------------------------------------------------
__global__ __launch_bounds__(256) void k_final(const float* __restrict__ H,
                                               const float* __restrict__ Wfc,
                                               const float* __restrict__ bfc,
                                               float* __restrict__ out) {
    __shared__ float ls[64 * 65];
    __shared__ float wl[64 * 4];
    const int tid = threadIdx.x;
    const int row0 = blockIdx.x * 64;
    for (int i = tid; i < 64 * 4; i += 256) wl[i] = Wfc[i];
    for (int i = tid; i < 64 * 64; i += 256) {
        int r = i >> 6, k = i & 63;
        int row = row0 + r;
        ls[r * 65 + k] = (row < N_NODES) ? H[row * 64 + k] : 0.f;
    }
    __syncthreads();
    int n = tid >> 2, c = tid & 3;
    int row = row0 + n;
    if (row >= N_NODES) return;
    float acc = bfc[c];
#pragma unroll
    for (int k = 0; k < 64; ++k) acc = fmaf(ls[n * 65 + k], wl[k * 4 + c], acc);
    out[row * 4 + c] = acc;
}

// ---------------------------------------------------------------------------
extern "C" void kernel_launch(void* const* d_in, const int* in_sizes, int n_in,
                              void* d_out, int out_size, void* d_ws, size_t ws_size,
                              hipStream_t stream) {
    const float* x   = (const float*)d_in[0];
    const int*   ei  = (const int*)d_in[1];
    const float* W1  = (const float*)d_in[2];
    const float* b1  = (const float*)d_in[3];
    const float* W2  = (const float*)d_in[4];
    const float* b2  = (const float*)d_in[5];
    const float* Wfc = (const float*)d_in[6];
    const float* bfc = (const float*)d_in[7];
    float* out = (float*)d_out;

    // workspace layout (4B words): 1024 + NPAD + NBUCK*CAP + 2*N*64  ~= 58.8 MB
    int*          bcnt = (int*)d_ws;                       // 1024
    float*        dinv = (float*)(bcnt + 1024);            // NPAD
    unsigned int* ebuf = (unsigned int*)(dinv + NPAD);     // NBUCK*CAP = 1801728
    float*        bufA = (float*)(ebuf + (size_t)NBUCK * CAP);  // N*64
    float*        bufB = bufA + (size_t)N_NODES * 64;           // N*64

    const int* src = ei;
    const int* dst = ei + N_EDGES;

    // bucket the edges + per-node dinv
    k_zero<<<4, 256, 0, stream>>>(bcnt);
    k_bucket<<<2048, 256, 0, stream>>>(src, dst, bcnt, ebuf);
    k_degb<<<NBUCK, 256, 0, stream>>>(ebuf, bcnt, dinv);

    // ---- layer 1 ----
    k_gemm<128, false><<<N_NODES / 16, 256, 0, stream>>>(x, W1, bufA);
    k_aggb<<<NBUCK, 256, 0, stream>>>(ebuf, bcnt, dinv, bufA, b1, bufB);

    // ---- layer 2 ----
    k_gemm<64, true><<<N_NODES / 16, 256, 0, stream>>>(bufB, W2, bufA);
    k_aggb<<<NBUCK, 256, 0, stream>>>(ebuf, bcnt, dinv, bufA, b2, bufB);

    // ---- final FC ----
    k_final<<<(N_NODES + 63) / 64, 256, 0, stream>>>(bufB, Wfc, bfc, out);
}

// Round 4
// 374.938 us; speedup vs baseline: 5.2779x; 5.2779x over previous
//
#include <hip/hip_runtime.h>

#define N_NODES 100000
#define N_EDGES 1600000
#define NEG_SLOPE 0.01f
#define NPAD 102400
#define NBLK_SCAN 391   // ceil(100000/256)

// ---------------------------------------------------------------------------
// deg[i] = 1 (self loop), then += 1 per incoming edge (dst). Int atomics.
// ---------------------------------------------------------------------------
__global__ void k_deg_init(int* __restrict__ deg) {
    int i = blockIdx.x * 256 + threadIdx.x;
    if (i < N_NODES) deg[i] = 1;
}

__global__ void k_deg_count(const int* __restrict__ dst, int* __restrict__ deg) {
    int idx = blockIdx.x * blockDim.x + threadIdx.x;
    int stride = gridDim.x * blockDim.x;
    for (int e = idx; e < N_EDGES; e += stride) atomicAdd(&deg[dst[e]], 1);
}

__global__ void k_dinv(const int* __restrict__ deg, float* __restrict__ dinv) {
    int i = blockIdx.x * 256 + threadIdx.x;
    if (i < N_NODES) dinv[i] = rsqrtf((float)deg[i]);
}

// ---------------------------------------------------------------------------
// Exclusive scan of in-degree (deg-1) into cur[]: 3-kernel block scan.
// ---------------------------------------------------------------------------
__global__ __launch_bounds__(256) void k_scan1(const int* __restrict__ deg,
                                               int* __restrict__ cur,
                                               int* __restrict__ bsum) {
    __shared__ int sd[256];
    int t = threadIdx.x;
    int gid = blockIdx.x * 256 + t;
    int v = (gid < N_NODES) ? (deg[gid] - 1) : 0;
    sd[t] = v;
    __syncthreads();
    for (int off = 1; off < 256; off <<= 1) {
        int add = (t >= off) ? sd[t - off] : 0;
        __syncthreads();
        sd[t] += add;
        __syncthreads();
    }
    cur[gid] = sd[t] - v;  // exclusive
    if (t == 255) bsum[blockIdx.x] = sd[255];
}

__global__ __launch_bounds__(512) void k_scan2(int* __restrict__ bsum) {
    __shared__ int sd[512];
    int t = threadIdx.x;
    int v = (t < NBLK_SCAN) ? bsum[t] : 0;
    sd[t] = v;
    __syncthreads();
    for (int off = 1; off < 512; off <<= 1) {
        int add = (t >= off) ? sd[t - off] : 0;
        __syncthreads();
        sd[t] += add;
        __syncthreads();
    }
    if (t < NBLK_SCAN) bsum[t] = sd[t] - v;  // exclusive
}

__global__ void k_scan3(int* __restrict__ cur, const int* __restrict__ bsum) {
    int gid = blockIdx.x * 256 + threadIdx.x;
    cur[gid] += bsum[blockIdx.x];
}

// ---------------------------------------------------------------------------
// CSR fill: slot = cur[dst]++ ; csr[slot] = src. After: cur[d] = end offset.
// Nontemporal store to cut write-allocate churn on the scattered 4B stores.
// ---------------------------------------------------------------------------
__global__ void k_fill(const int* __restrict__ src, const int* __restrict__ dst,
                       int* __restrict__ cur, int* __restrict__ csr) {
    int idx = blockIdx.x * blockDim.x + threadIdx.x;
    int stride = gridDim.x * blockDim.x;
    for (int e = idx; e < N_EDGES; e += stride) {
        int d = dst[e];
        int slot = atomicAdd(&cur[d], 1);
        __builtin_nontemporal_store(src[e], &csr[slot]);
    }
}

// ---------------------------------------------------------------------------
// Y[N,64] = X[N,K] @ W[K,64]
// ---------------------------------------------------------------------------
template <int K, bool LEAKY>
__global__ __launch_bounds__(256) void k_gemm(const float* __restrict__ X,
                                              const float* __restrict__ W,
                                              float* __restrict__ Y) {
    __shared__ float ws[K * 64];
    __shared__ __align__(16) float xs[16][K];
    const int tid = threadIdx.x;
    for (int i = tid; i < K * 64; i += 256) ws[i] = W[i];
    const int row0 = blockIdx.x * 16;
    for (int i = tid; i < 16 * K; i += 256) {
        int r = i / K, k = i % K;
        float v = X[(row0 + r) * K + k];
        if (LEAKY) v = (v >= 0.f) ? v : NEG_SLOPE * v;
        xs[r][k] = v;
    }
    __syncthreads();
    const int c = tid & 63, rq = tid >> 6;
    float acc[4] = {0.f, 0.f, 0.f, 0.f};
    const float4* xs4 = reinterpret_cast<const float4*>(&xs[0][0]);
    for (int k = 0; k < K; k += 4) {
        float w0 = ws[(k + 0) * 64 + c];
        float w1 = ws[(k + 1) * 64 + c];
        float w2 = ws[(k + 2) * 64 + c];
        float w3 = ws[(k + 3) * 64 + c];
        const int kq = k >> 2;
#pragma unroll
        for (int j = 0; j < 4; ++j) {
            float4 xv = xs4[(rq * 4 + j) * (K / 4) + kq];
            acc[j] = fmaf(xv.x, w0, acc[j]);
            acc[j] = fmaf(xv.y, w1, acc[j]);
            acc[j] = fmaf(xv.z, w2, acc[j]);
            acc[j] = fmaf(xv.w, w3, acc[j]);
        }
    }
#pragma unroll
    for (int j = 0; j < 4; ++j)
        Y[(row0 + rq * 4 + j) * 64 + c] = acc[j];
}

// ---------------------------------------------------------------------------
// 64-wide node-parallel aggregation (layer 1). Wave per node, lane = feature.
// ---------------------------------------------------------------------------
__global__ __launch_bounds__(256) void k_agg(const int* __restrict__ cur,
                                             const int* __restrict__ csr,
                                             const float* __restrict__ dinv,
                                             const float* __restrict__ h,
                                             const float* __restrict__ b,
                                             float* __restrict__ out) {
    int node = blockIdx.x * 4 + (threadIdx.x >> 6);
    if (node >= N_NODES) return;
    int lane = threadIdx.x & 63;
    int start = (node == 0) ? 0 : cur[node - 1];
    int end = cur[node];
    start = __builtin_amdgcn_readfirstlane(start);
    end = __builtin_amdgcn_readfirstlane(end);
    float dv = dinv[node];
    float acc = h[(size_t)node * 64 + lane] * (dv * dv) + b[lane];
    int j = start;
    for (; j + 4 <= end; j += 4) {
        int s0 = csr[j], s1 = csr[j + 1], s2 = csr[j + 2], s3 = csr[j + 3];
        float w0 = dinv[s0] * dv, w1 = dinv[s1] * dv;
        float w2 = dinv[s2] * dv, w3 = dinv[s3] * dv;
        float h0 = h[(size_t)s0 * 64 + lane];
        float h1 = h[(size_t)s1 * 64 + lane];
        float h2 = h[(size_t)s2 * 64 + lane];
        float h3 = h[(size_t)s3 * 64 + lane];
        acc = fmaf(h0, w0, acc);
        acc = fmaf(h1, w1, acc);
        acc = fmaf(h2, w2, acc);
        acc = fmaf(h3, w3, acc);
    }
    for (; j < end; ++j) {
        int s = csr[j];
        acc = fmaf(h[(size_t)s * 64 + lane], dinv[s] * dv, acc);
    }
    out[(size_t)node * 64 + lane] = acc;
}

// ---------------------------------------------------------------------------
// Fold kernel: Wc[64,4] = W2[64,64] @ Wfc[64,4];  cfold[4] = b2^T Wfc + bfc
// One block, 256 threads (k = tid>>2, c = tid&3).
// ---------------------------------------------------------------------------
__global__ __launch_bounds__(256) void k_foldw(const float* __restrict__ W2,
                                               const float* __restrict__ b2,
                                               const float* __restrict__ Wfc,
                                               const float* __restrict__ bfc,
                                               float* __restrict__ Wc,
                                               float* __restrict__ cfold) {
    __shared__ float wf[64 * 4];
    int tid = threadIdx.x;
    wf[tid] = Wfc[tid];
    __syncthreads();
    int k = tid >> 2, c = tid & 3;
    float acc = 0.f;
#pragma unroll
    for (int j = 0; j < 64; ++j) acc = fmaf(W2[k * 64 + j], wf[j * 4 + c], acc);
    Wc[k * 4 + c] = acc;
    if (tid < 4) {
        float s = bfc[tid];
        for (int j = 0; j < 64; ++j) s = fmaf(b2[j], wf[j * 4 + tid], s);
        cfold[tid] = s;
    }
}

// ---------------------------------------------------------------------------
// G[N,4] = leaky(H)[N,64] @ Wc[64,4]. 64 rows/block, LDS-staged (k_final-like).
// ---------------------------------------------------------------------------
__global__ __launch_bounds__(256) void k_gemm4(const float* __restrict__ H,
                                               const float* __restrict__ Wc,
                                               float* __restrict__ G) {
    __shared__ float ls[64 * 65];
    __shared__ float wl[64 * 4];
    const int tid = threadIdx.x;
    const int row0 = blockIdx.x * 64;
    wl[tid] = Wc[tid];
    for (int i = tid; i < 64 * 64; i += 256) {
        int r = i >> 6, k = i & 63;
        int row = row0 + r;
        float v = (row < N_NODES) ? H[(size_t)row * 64 + k] : 0.f;
        ls[r * 65 + k] = (v >= 0.f) ? v : NEG_SLOPE * v;
    }
    __syncthreads();
    int n = tid >> 2, c = tid & 3;
    int row = row0 + n;
    if (row >= N_NODES) return;
    float acc = 0.f;
#pragma unroll
    for (int k = 0; k < 64; ++k) acc = fmaf(ls[n * 65 + k], wl[k * 4 + c], acc);
    G[(size_t)row * 4 + c] = acc;
}

// ---------------------------------------------------------------------------
// 4-wide aggregation (layer 2 folded): thread per node, float4 accumulator.
// out[d] = sum_{s in N(d)} G[s]*dinv[s]*dinv[d] + G[d]/deg[d] + cfold
// ---------------------------------------------------------------------------
__global__ __launch_bounds__(256) void k_agg4(const int* __restrict__ cur,
                                              const int* __restrict__ csr,
                                              const float* __restrict__ dinv,
                                              const float4* __restrict__ G,
                                              const float* __restrict__ cfold,
                                              float4* __restrict__ out) {
    int node = blockIdx.x * 256 + threadIdx.x;
    if (node >= N_NODES) return;
    int start = (node == 0) ? 0 : cur[node - 1];
    int end = cur[node];
    float dv = dinv[node];
    float4 g = G[node];
    float w0 = dv * dv;
    float4 acc;
    acc.x = fmaf(g.x, w0, cfold[0]);
    acc.y = fmaf(g.y, w0, cfold[1]);
    acc.z = fmaf(g.z, w0, cfold[2]);
    acc.w = fmaf(g.w, w0, cfold[3]);
    int j = start;
    for (; j + 4 <= end; j += 4) {
        int s0 = csr[j], s1 = csr[j + 1], s2 = csr[j + 2], s3 = csr[j + 3];
        float a0 = dinv[s0] * dv, a1 = dinv[s1] * dv;
        float a2 = dinv[s2] * dv, a3 = dinv[s3] * dv;
        float4 g0 = G[s0], g1 = G[s1], g2 = G[s2], g3 = G[s3];
        acc.x = fmaf(g0.x, a0, acc.x); acc.y = fmaf(g0.y, a0, acc.y);
        acc.z = fmaf(g0.z, a0, acc.z); acc.w = fmaf(g0.w, a0, acc.w);
        acc.x = fmaf(g1.x, a1, acc.x); acc.y = fmaf(g1.y, a1, acc.y);
        acc.z = fmaf(g1.z, a1, acc.z); acc.w = fmaf(g1.w, a1, acc.w);
        acc.x = fmaf(g2.x, a2, acc.x); acc.y = fmaf(g2.y, a2, acc.y);
        acc.z = fmaf(g2.z, a2, acc.z); acc.w = fmaf(g2.w, a2, acc.w);
        acc.x = fmaf(g3.x, a3, acc.x); acc.y = fmaf(g3.y, a3, acc.y);
        acc.z = fmaf(g3.z, a3, acc.z); acc.w = fmaf(g3.w, a3, acc.w);
    }
    for (; j < end; ++j) {
        int s = csr[j];
        float a = dinv[s] * dv;
        float4 gs = G[s];
        acc.x = fmaf(gs.x, a, acc.x); acc.y = fmaf(gs.y, a, acc.y);
        acc.z = fmaf(gs.z, a, acc.z); acc.w = fmaf(gs.w, a, acc.w);
    }
    out[node] = acc;
}

// ---------------------------------------------------------------------------
extern "C" void kernel_launch(void* const* d_in, const int* in_sizes, int n_in,
                              void* d_out, int out_size, void* d_ws, size_t ws_size,
                              hipStream_t stream) {
    const float* x   = (const float*)d_in[0];
    const int*   ei  = (const int*)d_in[1];
    const float* W1  = (const float*)d_in[2];
    const float* b1  = (const float*)d_in[3];
    const float* W2  = (const float*)d_in[4];
    const float* b2  = (const float*)d_in[5];
    const float* Wfc = (const float*)d_in[6];
    const float* bfc = (const float*)d_in[7];
    float* out = (float*)d_out;

    // workspace layout (4B elements)
    int*   deg   = (int*)d_ws;                       // NPAD
    int*   cur   = deg + NPAD;                       // NPAD
    float* dinv  = (float*)(cur + NPAD);             // NPAD
    int*   bsum  = (int*)(dinv + NPAD);              // 1024
    float* Wc    = (float*)(bsum + 1024);            // 256
    float* cfold = Wc + 256;                         // 4 (pad to 256)
    int*   csr   = (int*)(cfold + 256);              // N_EDGES (pad 1600512)
    float* bufA  = (float*)(csr + 1600512);          // N*64
    float* bufB  = bufA + (size_t)N_NODES * 64;      // N*64
    float* G     = bufB + (size_t)N_NODES * 64;      // N*4

    const int* src = ei;
    const int* dst = ei + N_EDGES;

    // degree (incl. self loop) + dinv
    k_deg_init<<<(N_NODES + 255) / 256, 256, 0, stream>>>(deg);
    k_deg_count<<<2048, 256, 0, stream>>>(dst, deg);
    k_dinv<<<(N_NODES + 255) / 256, 256, 0, stream>>>(deg, dinv);

    // CSR build
    k_scan1<<<NBLK_SCAN, 256, 0, stream>>>(deg, cur, bsum);
    k_scan2<<<1, 512, 0, stream>>>(bsum);
    k_scan3<<<NBLK_SCAN, 256, 0, stream>>>(cur, bsum);
    k_fill<<<2048, 256, 0, stream>>>(src, dst, cur, csr);

    // folded layer-2 weights (independent of graph work)
    k_foldw<<<1, 256, 0, stream>>>(W2, b2, Wfc, bfc, Wc, cfold);

    // ---- layer 1 ----
    k_gemm<128, false><<<N_NODES / 16, 256, 0, stream>>>(x, W1, bufA);
    k_agg<<<(N_NODES + 3) / 4, 256, 0, stream>>>(cur, csr, dinv, bufA, b1, bufB);

    // ---- layer 2 (folded): G = leaky(h1) @ (W2@Wfc); out = Agg(G) + cfold ----
    k_gemm4<<<(N_NODES + 63) / 64, 256, 0, stream>>>(bufB, Wc, G);
    k_agg4<<<(N_NODES + 255) / 256, 256, 0, stream>>>(cur, csr, dinv,
                                                      (const float4*)G, cfold,
                                                      (float4*)out);
}

// Round 5
// 293.443 us; speedup vs baseline: 6.7437x; 1.2777x over previous
//
#include <hip/hip_runtime.h>

#define N_NODES 100000
#define N_EDGES 1600000
#define NEG_SLOPE 0.01f
#define NPAD 102400
#define NBLK_SCAN 391   // ceil(100000/256)
#define NPART 16
#define PART_SZ 6250    // 16 * 6250 = 100000 exactly

// ---------------------------------------------------------------------------
// deg[i] = 1 (self loop), then += 1 per incoming edge (dst). Int atomics.
// ---------------------------------------------------------------------------
__global__ void k_deg_init(int* __restrict__ deg) {
    int i = blockIdx.x * 256 + threadIdx.x;
    if (i < N_NODES) deg[i] = 1;
}

__global__ void k_deg_count(const int* __restrict__ dst, int* __restrict__ deg) {
    int idx = blockIdx.x * blockDim.x + threadIdx.x;
    int stride = gridDim.x * blockDim.x;
    for (int e = idx; e < N_EDGES; e += stride) atomicAdd(&deg[dst[e]], 1);
}

__global__ void k_dinv(const int* __restrict__ deg, float* __restrict__ dinv) {
    int i = blockIdx.x * 256 + threadIdx.x;
    if (i < N_NODES) dinv[i] = rsqrtf((float)deg[i]);
}

// ---------------------------------------------------------------------------
// Exclusive scan of in-degree (deg-1) into cur[]: 3-kernel block scan.
// ---------------------------------------------------------------------------
__global__ __launch_bounds__(256) void k_scan1(const int* __restrict__ deg,
                                               int* __restrict__ cur,
                                               int* __restrict__ bsum) {
    __shared__ int sd[256];
    int t = threadIdx.x;
    int gid = blockIdx.x * 256 + t;
    int v = (gid < N_NODES) ? (deg[gid] - 1) : 0;
    sd[t] = v;
    __syncthreads();
    for (int off = 1; off < 256; off <<= 1) {
        int add = (t >= off) ? sd[t - off] : 0;
        __syncthreads();
        sd[t] += add;
        __syncthreads();
    }
    cur[gid] = sd[t] - v;  // exclusive
    if (t == 255) bsum[blockIdx.x] = sd[255];
}

__global__ __launch_bounds__(512) void k_scan2(int* __restrict__ bsum) {
    __shared__ int sd[512];
    int t = threadIdx.x;
    int v = (t < NBLK_SCAN) ? bsum[t] : 0;
    sd[t] = v;
    __syncthreads();
    for (int off = 1; off < 512; off <<= 1) {
        int add = (t >= off) ? sd[t - off] : 0;
        __syncthreads();
        sd[t] += add;
        __syncthreads();
    }
    if (t < NBLK_SCAN) bsum[t] = sd[t] - v;  // exclusive
}

__global__ void k_scan3(int* __restrict__ cur, const int* __restrict__ bsum) {
    int gid = blockIdx.x * 256 + threadIdx.x;
    cur[gid] += bsum[blockIdx.x];
}

// ---------------------------------------------------------------------------
// Partitioned CSR fill. Partition p = blockIdx%16 handles dst in
// [p*6250,(p+1)*6250) so each XCD's L2 keeps a hot ~800KB csr window and
// every csr line collects all its stores before one writeback.
// ---------------------------------------------------------------------------
__global__ __launch_bounds__(256) void k_fillp(const int* __restrict__ src,
                                               const int* __restrict__ dst,
                                               int* __restrict__ cur,
                                               int* __restrict__ csr) {
    const int p = blockIdx.x & (NPART - 1);
    const int q = blockIdx.x >> 4;
    const int lo = p * PART_SZ, hi = lo + PART_SZ;
    const int nthread = (gridDim.x >> 4) * 256;
    for (int e = q * 256 + threadIdx.x; e < N_EDGES; e += nthread) {
        int d = dst[e];
        if (d >= lo && d < hi) {
            int slot = atomicAdd(&cur[d], 1);
            csr[slot] = src[e];
        }
    }
}

// ---------------------------------------------------------------------------
// Y[N,64] = X[N,K] @ W[K,64]
// ---------------------------------------------------------------------------
template <int K, bool LEAKY>
__global__ __launch_bounds__(256) void k_gemm(const float* __restrict__ X,
                                              const float* __restrict__ W,
                                              float* __restrict__ Y) {
    __shared__ float ws[K * 64];
    __shared__ __align__(16) float xs[16][K];
    const int tid = threadIdx.x;
    for (int i = tid; i < K * 64; i += 256) ws[i] = W[i];
    const int row0 = blockIdx.x * 16;
    for (int i = tid; i < 16 * K; i += 256) {
        int r = i / K, k = i % K;
        float v = X[(row0 + r) * K + k];
        if (LEAKY) v = (v >= 0.f) ? v : NEG_SLOPE * v;
        xs[r][k] = v;
    }
    __syncthreads();
    const int c = tid & 63, rq = tid >> 6;
    float acc[4] = {0.f, 0.f, 0.f, 0.f};
    const float4* xs4 = reinterpret_cast<const float4*>(&xs[0][0]);
    for (int k = 0; k < K; k += 4) {
        float w0 = ws[(k + 0) * 64 + c];
        float w1 = ws[(k + 1) * 64 + c];
        float w2 = ws[(k + 2) * 64 + c];
        float w3 = ws[(k + 3) * 64 + c];
        const int kq = k >> 2;
#pragma unroll
        for (int j = 0; j < 4; ++j) {
            float4 xv = xs4[(rq * 4 + j) * (K / 4) + kq];
            acc[j] = fmaf(xv.x, w0, acc[j]);
            acc[j] = fmaf(xv.y, w1, acc[j]);
            acc[j] = fmaf(xv.z, w2, acc[j]);
            acc[j] = fmaf(xv.w, w3, acc[j]);
        }
    }
#pragma unroll
    for (int j = 0; j < 4; ++j)
        Y[(row0 + rq * 4 + j) * 64 + c] = acc[j];
}

// ---------------------------------------------------------------------------
// 64-wide node-parallel aggregation (layer 1). Wave per node, lane = feature.
// ---------------------------------------------------------------------------
__global__ __launch_bounds__(256) void k_agg(const int* __restrict__ cur,
                                             const int* __restrict__ csr,
                                             const float* __restrict__ dinv,
                                             const float* __restrict__ h,
                                             const float* __restrict__ b,
                                             float* __restrict__ out) {
    int node = blockIdx.x * 4 + (threadIdx.x >> 6);
    if (node >= N_NODES) return;
    int lane = threadIdx.x & 63;
    int start = (node == 0) ? 0 : cur[node - 1];
    int end = cur[node];
    start = __builtin_amdgcn_readfirstlane(start);
    end = __builtin_amdgcn_readfirstlane(end);
    float dv = dinv[node];
    float acc = h[(size_t)node * 64 + lane] * (dv * dv) + b[lane];
    int j = start;
    for (; j + 4 <= end; j += 4) {
        int s0 = csr[j], s1 = csr[j + 1], s2 = csr[j + 2], s3 = csr[j + 3];
        float w0 = dinv[s0] * dv, w1 = dinv[s1] * dv;
        float w2 = dinv[s2] * dv, w3 = dinv[s3] * dv;
        float h0 = h[(size_t)s0 * 64 + lane];
        float h1 = h[(size_t)s1 * 64 + lane];
        float h2 = h[(size_t)s2 * 64 + lane];
        float h3 = h[(size_t)s3 * 64 + lane];
        acc = fmaf(h0, w0, acc);
        acc = fmaf(h1, w1, acc);
        acc = fmaf(h2, w2, acc);
        acc = fmaf(h3, w3, acc);
    }
    for (; j < end; ++j) {
        int s = csr[j];
        acc = fmaf(h[(size_t)s * 64 + lane], dinv[s] * dv, acc);
    }
    out[(size_t)node * 64 + lane] = acc;
}

// ---------------------------------------------------------------------------
// Fold kernel: Wc[64,4] = W2[64,64] @ Wfc[64,4];  cfold[4] = b2^T Wfc + bfc
// ---------------------------------------------------------------------------
__global__ __launch_bounds__(256) void k_foldw(const float* __restrict__ W2,
                                               const float* __restrict__ b2,
                                               const float* __restrict__ Wfc,
                                               const float* __restrict__ bfc,
                                               float* __restrict__ Wc,
                                               float* __restrict__ cfold) {
    __shared__ float wf[64 * 4];
    int tid = threadIdx.x;
    wf[tid] = Wfc[tid];
    __syncthreads();
    int k = tid >> 2, c = tid & 3;
    float acc = 0.f;
#pragma unroll
    for (int j = 0; j < 64; ++j) acc = fmaf(W2[k * 64 + j], wf[j * 4 + c], acc);
    Wc[k * 4 + c] = acc;
    if (tid < 4) {
        float s = bfc[tid];
        for (int j = 0; j < 64; ++j) s = fmaf(b2[j], wf[j * 4 + tid], s);
        cfold[tid] = s;
    }
}

// ---------------------------------------------------------------------------
// G[N,4] = leaky(H)[N,64] @ Wc[64,4]. 64 rows/block, LDS-staged.
// ---------------------------------------------------------------------------
__global__ __launch_bounds__(256) void k_gemm4(const float* __restrict__ H,
                                               const float* __restrict__ Wc,
                                               float* __restrict__ G) {
    __shared__ float ls[64 * 65];
    __shared__ float wl[64 * 4];
    const int tid = threadIdx.x;
    const int row0 = blockIdx.x * 64;
    wl[tid] = Wc[tid];
    for (int i = tid; i < 64 * 64; i += 256) {
        int r = i >> 6, k = i & 63;
        int row = row0 + r;
        float v = (row < N_NODES) ? H[(size_t)row * 64 + k] : 0.f;
        ls[r * 65 + k] = (v >= 0.f) ? v : NEG_SLOPE * v;
    }
    __syncthreads();
    int n = tid >> 2, c = tid & 3;
    int row = row0 + n;
    if (row >= N_NODES) return;
    float acc = 0.f;
#pragma unroll
    for (int k = 0; k < 64; ++k) acc = fmaf(ls[n * 65 + k], wl[k * 4 + c], acc);
    G[(size_t)row * 4 + c] = acc;
}

// ---------------------------------------------------------------------------
// 4-wide aggregation (layer 2 folded): thread per node, float4 accumulator.
// ---------------------------------------------------------------------------
__global__ __launch_bounds__(256) void k_agg4(const int* __restrict__ cur,
                                              const int* __restrict__ csr,
                                              const float* __restrict__ dinv,
                                              const float4* __restrict__ G,
                                              const float* __restrict__ cfold,
                                              float4* __restrict__ out) {
    int node = blockIdx.x * 256 + threadIdx.x;
    if (node >= N_NODES) return;
    int start = (node == 0) ? 0 : cur[node - 1];
    int end = cur[node];
    float dv = dinv[node];
    float4 g = G[node];
    float w0 = dv * dv;
    float4 acc;
    acc.x = fmaf(g.x, w0, cfold[0]);
    acc.y = fmaf(g.y, w0, cfold[1]);
    acc.z = fmaf(g.z, w0, cfold[2]);
    acc.w = fmaf(g.w, w0, cfold[3]);
    int j = start;
    for (; j + 4 <= end; j += 4) {
        int s0 = csr[j], s1 = csr[j + 1], s2 = csr[j + 2], s3 = csr[j + 3];
        float a0 = dinv[s0] * dv, a1 = dinv[s1] * dv;
        float a2 = dinv[s2] * dv, a3 = dinv[s3] * dv;
        float4 g0 = G[s0], g1 = G[s1], g2 = G[s2], g3 = G[s3];
        acc.x = fmaf(g0.x, a0, acc.x); acc.y = fmaf(g0.y, a0, acc.y);
        acc.z = fmaf(g0.z, a0, acc.z); acc.w = fmaf(g0.w, a0, acc.w);
        acc.x = fmaf(g1.x, a1, acc.x); acc.y = fmaf(g1.y, a1, acc.y);
        acc.z = fmaf(g1.z, a1, acc.z); acc.w = fmaf(g1.w, a1, acc.w);
        acc.x = fmaf(g2.x, a2, acc.x); acc.y = fmaf(g2.y, a2, acc.y);
        acc.z = fmaf(g2.z, a2, acc.z); acc.w = fmaf(g2.w, a2, acc.w);
        acc.x = fmaf(g3.x, a3, acc.x); acc.y = fmaf(g3.y, a3, acc.y);
        acc.z = fmaf(g3.z, a3, acc.z); acc.w = fmaf(g3.w, a3, acc.w);
    }
    for (; j < end; ++j) {
        int s = csr[j];
        float a = dinv[s] * dv;
        float4 gs = G[s];
        acc.x = fmaf(gs.x, a, acc.x); acc.y = fmaf(gs.y, a, acc.y);
        acc.z = fmaf(gs.z, a, acc.z); acc.w = fmaf(gs.w, a, acc.w);
    }
    out[node] = acc;
}

// ---------------------------------------------------------------------------
extern "C" void kernel_launch(void* const* d_in, const int* in_sizes, int n_in,
                              void* d_out, int out_size, void* d_ws, size_t ws_size,
                              hipStream_t stream) {
    const float* x   = (const float*)d_in[0];
    const int*   ei  = (const int*)d_in[1];
    const float* W1  = (const float*)d_in[2];
    const float* b1  = (const float*)d_in[3];
    const float* W2  = (const float*)d_in[4];
    const float* b2  = (const float*)d_in[5];
    const float* Wfc = (const float*)d_in[6];
    const float* bfc = (const float*)d_in[7];
    float* out = (float*)d_out;

    // workspace layout (4B elements)
    int*   deg   = (int*)d_ws;                       // NPAD
    int*   cur   = deg + NPAD;                       // NPAD
    float* dinv  = (float*)(cur + NPAD);             // NPAD
    int*   bsum  = (int*)(dinv + NPAD);              // 1024
    float* Wc    = (float*)(bsum + 1024);            // 256
    float* cfold = Wc + 256;                         // 4 (pad to 256)
    int*   csr   = (int*)(cfold + 256);              // N_EDGES (pad 1600512)
    float* bufA  = (float*)(csr + 1600512);          // N*64
    float* bufB  = bufA + (size_t)N_NODES * 64;      // N*64
    float* G     = bufB + (size_t)N_NODES * 64;      // N*4

    const int* src = ei;
    const int* dst = ei + N_EDGES;

    // degree (incl. self loop) + dinv
    k_deg_init<<<(N_NODES + 255) / 256, 256, 0, stream>>>(deg);
    k_deg_count<<<2048, 256, 0, stream>>>(dst, deg);
    k_dinv<<<(N_NODES + 255) / 256, 256, 0, stream>>>(deg, dinv);

    // CSR build (partitioned fill for L2-resident store windows)
    k_scan1<<<NBLK_SCAN, 256, 0, stream>>>(deg, cur, bsum);
    k_scan2<<<1, 512, 0, stream>>>(bsum);
    k_scan3<<<NBLK_SCAN, 256, 0, stream>>>(cur, bsum);
    k_fillp<<<2048, 256, 0, stream>>>(src, dst, cur, csr);

    // folded layer-2 weights
    k_foldw<<<1, 256, 0, stream>>>(W2, b2, Wfc, bfc, Wc, cfold);

    // ---- layer 1 ----
    k_gemm<128, false><<<N_NODES / 16, 256, 0, stream>>>(x, W1, bufA);
    k_agg<<<(N_NODES + 3) / 4, 256, 0, stream>>>(cur, csr, dinv, bufA, b1, bufB);

    // ---- layer 2 (folded): G = leaky(h1) @ (W2@Wfc); out = Agg(G) + cfold ----
    k_gemm4<<<(N_NODES + 63) / 64, 256, 0, stream>>>(bufB, Wc, G);
    k_agg4<<<(N_NODES + 255) / 256, 256, 0, stream>>>(cur, csr, dinv,
                                                      (const float4*)G, cfold,
                                                      (float4*)out);
}